// Round 18
// baseline (83.195 us; speedup 1.0000x reference)
//
#include <hip/hip_runtime.h>
#include <hip/hip_bf16.h>

typedef __bf16 bf16x8 __attribute__((ext_vector_type(8)));
typedef float f32x4 __attribute__((ext_vector_type(4)));
typedef unsigned short ushort_t;

// B=8, P=64, S=512, D=512, L=64
#define SS 512
#define DD 512
#define LL 64

__device__ __forceinline__ ushort_t f2b(float f) {
    union { float f; unsigned u; } x; x.f = f;
    unsigned r = x.u + 0x7FFFu + ((x.u >> 16) & 1u);
    return (ushort_t)(r >> 16);
}

// async global->LDS, 16B per lane; LDS dest = wave-uniform base + lane*16
__device__ __forceinline__ void async16(const void* g, void* l) {
    __builtin_amdgcn_global_load_lds(
        (const __attribute__((address_space(1))) unsigned int*)g,
        (__attribute__((address_space(3))) unsigned int*)l, 16, 0, 0);
}

// =====================================================================
// 256x256 8-wave pipelined GEMM core (R4-proven) — k_out256 only.
// =====================================================================
__device__ __forceinline__ void stage_tile(const ushort_t* __restrict__ A, int lda,
                                           const ushort_t* __restrict__ Bt, int ldb,
                                           int k0, ushort_t* buf) {
    const int t = threadIdx.x;
    const int wbase = (t >> 6) << 10;              // wid*1024 bytes
#pragma unroll
    for (int p = 0; p < 2; p++) {
        int row = (p << 7) + (t >> 2);             // dest row = x>>6
        int kg = (t & 3) ^ ((t >> 3) & 3);         // slot ^ ((row>>1)&3)
        async16(A + (size_t)row * lda + k0 + kg * 8,
                (char*)buf + (p << 13) + wbase);
        async16(Bt + (size_t)row * ldb + k0 + kg * 8,
                (char*)(buf + 8192) + (p << 13) + wbase);
    }
}

__device__ __forceinline__ void gemm256(const ushort_t* __restrict__ A, int lda,
                                        const ushort_t* __restrict__ Bt, int ldb,
                                        ushort_t* lds, f32x4 (&acc)[8][4]) {
    const int t = threadIdx.x;
    const int lane = t & 63, wid = t >> 6;
    const int wm = wid >> 2, wn = wid & 3;
    const int r15 = lane & 15, kg = lane >> 4;
    const int sx = ((kg ^ ((r15 >> 1) & 3)) << 4);   // swizzled 16B slot byte
    const f32x4 z4 = {0.f, 0.f, 0.f, 0.f};
#pragma unroll
    for (int i = 0; i < 8; i++)
#pragma unroll
        for (int j = 0; j < 4; j++) acc[i][j] = z4;

    stage_tile(A, lda, Bt, ldb, 0, lds);            // tile 0 -> buf0
    stage_tile(A, lda, Bt, ldb, 32, lds + 16384);   // tile 1 -> buf1

    for (int T = 0; T < 16; ++T) {
        if (T < 15) asm volatile("s_waitcnt vmcnt(4)" ::: "memory");
        else        asm volatile("s_waitcnt vmcnt(0)" ::: "memory");
        __builtin_amdgcn_s_barrier();
        __builtin_amdgcn_sched_barrier(0);
        const ushort_t* bufA = lds + (T % 3) * 16384;
        const ushort_t* bufB = bufA + 8192;
        const char* pa = (const char*)bufA + (wm * 128 + r15) * 64 + sx;
        const char* pb = (const char*)bufB + (wn * 64 + r15) * 64 + sx;
        bf16x8 af[8], bf[4];
#pragma unroll
        for (int mf = 0; mf < 8; mf++) af[mf] = *(const bf16x8*)(pa + mf * 1024);
#pragma unroll
        for (int nf = 0; nf < 4; nf++) bf[nf] = *(const bf16x8*)(pb + nf * 1024);
        if (T + 2 < 16)
            stage_tile(A, lda, Bt, ldb, (T + 2) * 32, lds + ((T + 2) % 3) * 16384);
#pragma unroll
        for (int mf = 0; mf < 8; mf++)
#pragma unroll
            for (int nf = 0; nf < 4; nf++)
                acc[mf][nf] = __builtin_amdgcn_mfma_f32_16x16x32_bf16(
                    af[mf], bf[nf], acc[mf][nf], 0, 0, 0);
    }
    __syncthreads();    // all reads done; LDS free for epilogue reuse
}

// =====================================================================
// U-core R18: BM=256, BN=256, 8 waves (2m x 4n), acc[8][4].
// A: predB bf16 via gload_lds, 3 x 16KB (48KB), swizzled frag layout.
// B: W1 f32 [32k][256e] tile via gload_lds COALESCED (rows 1KB dense),
//    3 x 32KB (96KB). Transpose happens at READ time: per-lane
//    ds_read_b32 column reads + cvt f32->bf16.
//    Bank swizzle (rule #21, both sides): dest chunk c of row r holds
//    source chunk (c + 2*((r>>3)&3)) & 63 -> read bank index
//    (nf*4 + (r15>>2) - 2*kg) mod 8 covers each value exactly 2x
//    => 2-way conflict = free (m136).
// Schedule: single top barrier per step, counted vmcnt(6)
//    (6 issues/step: 4 B + 2 A, staged T+2). LDS 144KB, 1 block/CU
//    (occupancy shown irrelevant: R15~=R16).
// =====================================================================
__device__ __forceinline__ void stageA2(const ushort_t* __restrict__ A,
                                        int k0, ushort_t* buf) {
    const int t = threadIdx.x;
    const int wbase = (t >> 6) << 10;
#pragma unroll
    for (int p = 0; p < 2; p++) {
        int row = (p << 7) + (t >> 2);
        int kg = (t & 3) ^ ((t >> 3) & 3);
        async16(A + (size_t)row * DD + k0 + kg * 8, (char*)buf + (p << 13) + wbase);
    }
}

__device__ __forceinline__ void stageB_w1(const float* __restrict__ W1le,
                                          int k0, ushort_t* buf) {
    const int t = threadIdx.x;
#pragma unroll
    for (int p = 0; p < 4; p++) {
        int o = p * 8192 + t * 16;                 // dest byte 0..32767
        int row = o >> 10;                         // 0..31 (1KB f32 rows)
        int c = (o >> 4) & 63;                     // dest 16B chunk in row
        int sc = (c + 2 * ((row >> 3) & 3)) & 63;  // rotated source chunk
        async16(W1le + (size_t)(k0 + row) * DD + sc * 4, (char*)buf + o);
    }
}

__device__ __forceinline__ void gemm256_w1lds(const ushort_t* __restrict__ predB,
                                              const float* __restrict__ W1le,
                                              ushort_t* lds, f32x4 (&acc)[8][4]) {
    const int t = threadIdx.x;
    const int lane = t & 63, wid = t >> 6;
    const int wm = wid >> 2, wn = wid & 3;
    const int r15 = lane & 15, kg = lane >> 4;
    const int sx = ((kg ^ ((r15 >> 1) & 3)) << 4);
    const f32x4 z4 = {0.f, 0.f, 0.f, 0.f};
#pragma unroll
    for (int i = 0; i < 8; i++)
#pragma unroll
        for (int j = 0; j < 4; j++) acc[i][j] = z4;

    ushort_t* Ab = lds;                 // 3 x 8192 ushorts (16KB each)
    ushort_t* Bb = lds + 24576;         // 3 x 16384 ushorts (32KB each)

    stageB_w1(W1le, 0, Bb);                          // B(0) [4 vm]
    stageA2(predB, 0, Ab);                           // A(0) [2 vm]
    stageB_w1(W1le, 32, Bb + 16384);                 // B(1) [4 vm]
    stageA2(predB, 32, Ab + 8192);                   // A(1) [2 vm]

    for (int T = 0; T < 16; ++T) {
        if (T < 15) asm volatile("s_waitcnt vmcnt(6)" ::: "memory");
        else        asm volatile("s_waitcnt vmcnt(0)" ::: "memory");
        __builtin_amdgcn_s_barrier();
        __builtin_amdgcn_sched_barrier(0);
        const char* bF = (const char*)(Bb + (T % 3) * 16384);
        // B frags: column reads, rot-swizzled chunks (2-way free)
        bf16x8 bf[4];
#pragma unroll
        for (int nf = 0; nf < 4; nf++) {
            int ebase = wn * 16 + nf * 4 + (r15 >> 2);    // e>>2 (chunk index)
#pragma unroll
            for (int j = 0; j < 8; j++) {
                int chunk = (ebase - 2 * kg) & 63;
                float v = *(const float*)(bF + (size_t)(kg * 8 + j) * 1024
                                          + (chunk << 4) + (r15 & 3) * 4);
                bf[nf][j] = (__bf16)v;
            }
        }
        if (T + 2 < 16) {
            stageB_w1(W1le, (T + 2) * 32, Bb + ((T + 2) % 3) * 16384);
            stageA2(predB, (T + 2) * 32, Ab + ((T + 2) % 3) * 8192);
        }
        const char* pa = (const char*)(Ab + (T % 3) * 8192)
                         + (wm * 128 + r15) * 64 + sx;
        bf16x8 af[8];
#pragma unroll
        for (int mf = 0; mf < 8; mf++) af[mf] = *(const bf16x8*)(pa + mf * 1024);
#pragma unroll
        for (int mf = 0; mf < 8; mf++)
#pragma unroll
            for (int nf = 0; nf < 4; nf++)
                acc[mf][nf] = __builtin_amdgcn_mfma_f32_16x16x32_bf16(
                    af[mf], bf[nf], acc[mf][nf], 0, 0, 0);
    }
    __syncthreads();
}

// =====================================================================
// merged small + U kernel, 512 threads, 144KB dynamic LDS.
// blocks [0,180): small GEMMs. blocks [180,436): U GEMM (XCD-swizzled).
// =====================================================================
__global__ void __launch_bounds__(512, 1) k_U_small(
    const ushort_t* __restrict__ predB, const float* __restrict__ W1,
    ushort_t* __restrict__ UB,
    const ushort_t* __restrict__ spanB, const ushort_t* __restrict__ WaB,
    const ushort_t* __restrict__ WpB, const ushort_t* __restrict__ W2bT,
    const ushort_t* __restrict__ W2aT,
    const float* __restrict__ ba_, const float* __restrict__ bp_,
    const float* __restrict__ wa, const float* __restrict__ wp,
    float* ascore, float* pscore, float* spanW2, float* predW2) {
    extern __shared__ ushort_t lds[];
    const f32x4 z4 = {0.f, 0.f, 0.f, 0.f};
    const int t = threadIdx.x, lane = t & 63;
    const int r15 = lane & 15, kg = lane >> 4;
    if (blockIdx.x >= 180) {
        // ---------------- U role ----------------
        f32x4 acc[8][4];
        int u = blockIdx.x - 180;                        // 0..255
        int swz = (u & 7) * 32 + (u >> 3);               // bijective 256->256
        int m0 = (swz & 1) * 256, n0 = (swz >> 1) * 256;
        int l = n0 >> 9, e0 = n0 & 511;
        gemm256_w1lds(predB + (size_t)m0 * DD,
                      W1 + ((size_t)l * DD) * DD + e0, lds, acc);
        const int wid = t >> 6;
        const int wm = wid >> 2, wn = wid & 3;
        ushort_t* my = lds + wid * 4096;                 // 8KB/wave -> 64KB
        int gm = m0 + wm * 128, gn = n0 + wn * 64;
#pragma unroll
        for (int ch = 0; ch < 2; ch++) {
#pragma unroll
            for (int mf2 = 0; mf2 < 4; mf2++)
#pragma unroll
                for (int nf = 0; nf < 4; nf++)
#pragma unroll
                    for (int j = 0; j < 4; j++)
                        my[(mf2 * 16 + kg * 4 + j) * 64 + nf * 16 + r15] =
                            f2b(acc[ch * 4 + mf2][nf][j]);
#pragma unroll
            for (int it = 0; it < 8; it++) {
                int lr = it * 8 + (lane >> 3);
                bf16x8 v = *(const bf16x8*)(my + lr * 64 + (lane & 7) * 8);
                *(bf16x8*)(UB + (size_t)(gm + ch * 64 + lr) * 32768 + gn
                           + (lane & 7) * 8) = v;
            }
            __syncthreads();   // ch=0 reads done before ch=1 overwrites
        }
        return;
    }
    // ---------------- small role (512 threads; lower 256 active) ----------
    const bool act = t < 256;
    ushort_t* As = lds;              // 8KB
    ushort_t* Bs = lds + 4096;       // 8KB
    const int wid4 = (t >> 6) & 3;
    const int o0 = wid4 * 1024 + lane * 16;
    int blk = blockIdx.x;
    if (blk < 144) {
        const ushort_t *A, *Bt; const float *bias, *w; float* sc; int m0, n0;
        if (blk < 128) { A = spanB; Bt = WaB; bias = ba_; w = wa; sc = ascore;
                         m0 = (blk >> 2) * 128; n0 = (blk & 3) * 128; }
        else { int q = blk - 128; A = predB; Bt = WpB; bias = bp_; w = wp; sc = pscore;
               m0 = (q >> 2) * 128; n0 = (q & 3) * 128; }
        const ushort_t* Ab2 = A + (size_t)m0 * DD;
        const ushort_t* Bb2 = Bt + (size_t)n0 * DD;
        f32x4 acc[4][4];
#pragma unroll
        for (int i = 0; i < 4; i++)
#pragma unroll
            for (int j = 0; j < 4; j++) acc[i][j] = z4;
        int wr = (wid4 >> 1) * 64, wc = (wid4 & 1) * 64;
        for (int k0 = 0; k0 < DD; k0 += 32) {
            if (act) {
#pragma unroll
                for (int p = 0; p < 2; p++) {
                    int o = o0 + p * 4096;
                    async16(Ab2 + (size_t)(o >> 6) * DD + k0 + ((o & 63) >> 1), (char*)As + o);
                    async16(Bb2 + (size_t)(o >> 6) * DD + k0 + ((o & 63) >> 1), (char*)Bs + o);
                }
            }
            __syncthreads();
            if (act) {
                bf16x8 af[4], bf[4];
#pragma unroll
                for (int mf = 0; mf < 4; mf++)
                    af[mf] = *(const bf16x8*)(As + (wr + mf * 16 + r15) * 32 + kg * 8);
#pragma unroll
                for (int nf = 0; nf < 4; nf++)
                    bf[nf] = *(const bf16x8*)(Bs + (wc + nf * 16 + r15) * 32 + kg * 8);
#pragma unroll
                for (int mf = 0; mf < 4; mf++)
#pragma unroll
                    for (int nf = 0; nf < 4; nf++)
                        acc[mf][nf] = __builtin_amdgcn_mfma_f32_16x16x32_bf16(
                            af[mf], bf[nf], acc[mf][nf], 0, 0, 0);
            }
            __syncthreads();
        }
        if (act) {
#pragma unroll
            for (int mf = 0; mf < 4; mf++)
#pragma unroll
                for (int j = 0; j < 4; j++) {
                    float v = 0.f;
#pragma unroll
                    for (int nf = 0; nf < 4; nf++) {
                        int col = n0 + wc + nf * 16 + r15;
                        float c = acc[mf][nf][j] + bias[col];
                        if (c > 0.f) v += c * w[col];
                    }
                    v += __shfl_xor(v, 1); v += __shfl_xor(v, 2);
                    v += __shfl_xor(v, 4); v += __shfl_xor(v, 8);
                    if (r15 == 0) atomicAdd(&sc[m0 + wr + mf * 16 + kg * 4 + j], v);
                }
        }
    } else {
        int q = blk - 144;
        const ushort_t *A, *Bt; float* C; int m0;
        if (q < 32) { A = spanB; Bt = W2bT; C = spanW2; m0 = q * 128; }
        else { A = predB; Bt = W2aT; C = predW2; m0 = (q - 32) * 128; }
        const ushort_t* Ab2 = A + (size_t)m0 * DD;
        f32x4 acc[4][2];
#pragma unroll
        for (int i = 0; i < 4; i++) { acc[i][0] = z4; acc[i][1] = z4; }
        int wr = (wid4 >> 1) * 64, wc = (wid4 & 1) * 32;
        for (int k0 = 0; k0 < DD; k0 += 32) {
            if (act) {
#pragma unroll
                for (int p = 0; p < 2; p++) {
                    int o = o0 + p * 4096;
                    async16(Ab2 + (size_t)(o >> 6) * DD + k0 + ((o & 63) >> 1), (char*)As + o);
                }
                int o = o0;
                async16(Bt + (size_t)(o >> 6) * DD + k0 + ((o & 63) >> 1), (char*)Bs + o);
            }
            __syncthreads();
            if (act) {
                bf16x8 af[4], bf[2];
#pragma unroll
                for (int mf = 0; mf < 4; mf++)
                    af[mf] = *(const bf16x8*)(As + (wr + mf * 16 + r15) * 32 + kg * 8);
#pragma unroll
                for (int nf = 0; nf < 2; nf++)
                    bf[nf] = *(const bf16x8*)(Bs + (wc + nf * 16 + r15) * 32 + kg * 8);
#pragma unroll
                for (int mf = 0; mf < 4; mf++)
#pragma unroll
                    for (int nf = 0; nf < 2; nf++)
                        acc[mf][nf] = __builtin_amdgcn_mfma_f32_16x16x32_bf16(
                            af[mf], bf[nf], acc[mf][nf], 0, 0, 0);
            }
            __syncthreads();
        }
        if (act) {
#pragma unroll
            for (int mf = 0; mf < 4; mf++)
#pragma unroll
                for (int nf = 0; nf < 2; nf++)
#pragma unroll
                    for (int j = 0; j < 4; j++) {
                        int m = m0 + wr + mf * 16 + kg * 4 + j;
                        int n = wc + nf * 16 + r15;
                        C[(size_t)m * LL + n] = acc[mf][nf][j];
                    }
        }
    }
}

// ---- out GEMM 256 + fused epilogue: per b, C[s, p*64+l] ----
__global__ void __launch_bounds__(512, 2) k_out256(const ushort_t* __restrict__ spanB,
    const ushort_t* __restrict__ UB, const float* __restrict__ spanW2,
    const float* __restrict__ predW2, const float* __restrict__ ascore,
    const float* __restrict__ pscore, const float* __restrict__ bias,
    float* __restrict__ out) {
    extern __shared__ ushort_t lds[];
    f32x4 acc[8][4];
    int swz = (blockIdx.x & 7) * 32 + (blockIdx.x >> 3);   // 256 -> 256 bijective
    int b = swz >> 5, r = swz & 31;
    int m0 = (r & 1) * 256, n0 = (r >> 1) * 256;
    gemm256(spanB + ((size_t)b * SS + m0) * DD, DD,
            UB + ((size_t)b * 4096 + n0) * DD, DD, lds, acc);
    const int t = threadIdx.x, lane = t & 63, wid = t >> 6;
    const int wm = wid >> 2, wn = wid & 3, r15 = lane & 15, kg = lane >> 4;
    float cn[4]; int nn[4];
#pragma unroll
    for (int nf = 0; nf < 4; nf++) {
        int n = n0 + wn * 64 + nf * 16 + r15;
        nn[nf] = n;
        cn[nf] = bias[n & 63] + predW2[b * 4096 + n] + pscore[b * 64 + (n >> 6)];
    }
#pragma unroll
    for (int mf = 0; mf < 8; mf++)
#pragma unroll
        for (int j = 0; j < 4; j++) {
            int s = m0 + wm * 128 + mf * 16 + kg * 4 + j;
            float as_ = ascore[b * SS + s];
            const float* sw = spanW2 + ((size_t)b * SS + s) * LL;
#pragma unroll
            for (int nf = 0; nf < 4; nf++) {
                int n = nn[nf], l = n & 63, p = n >> 6;
                float v = acc[mf][nf][j] + cn[nf] + as_ + sw[l];
                if (l == LL - 1) v = 0.f;
                out[(((size_t)b * 64 + p) * SS + s) * LL + l] = v;
            }
        }
}

// ---- fast prep: bf16 conversions, gather, W2^T, labels, score zero-init ----
__global__ __launch_bounds__(256) void k_prep(
    const float* __restrict__ span, const int* __restrict__ preds,
    const int* __restrict__ labels, const float* __restrict__ Wa,
    const float* __restrict__ Wp, const float* __restrict__ W2,
    ushort_t* spanB, ushort_t* predB, ushort_t* WaB, ushort_t* WpB,
    ushort_t* W2aT, ushort_t* W2bT, float* out, float* scores) {
    int blk = blockIdx.x;
    if (blk < 4096) {
        int id = blk * 256 + threadIdx.x;
        if (id < 524288) {
            float4 v = ((const float4*)span)[id];
            ((ushort4*)spanB)[id] = make_ushort4(f2b(v.x), f2b(v.y), f2b(v.z), f2b(v.w));
        } else if (id < 589824) {
            int j = id - 524288;
            int row = j >> 7, c4 = j & 127;
            int b = row >> 6;
            int idx = preds[row];
            float4 v = ((const float4*)(span + ((size_t)(b * SS + idx)) * DD))[c4];
            ((ushort4*)(predB + (size_t)row * DD))[c4] =
                make_ushort4(f2b(v.x), f2b(v.y), f2b(v.z), f2b(v.w));
        } else if (id < 851968) {
            int k = id - 589824;
            out[16777216 + k] = (float)labels[k];
        } else if (id < 917504) {
            int j = id - 851968;
            float4 v = ((const float4*)Wa)[j];
            ((ushort4*)WaB)[j] = make_ushort4(f2b(v.x), f2b(v.y), f2b(v.z), f2b(v.w));
        } else if (id < 983040) {
            int j = id - 917504;
            float4 v = ((const float4*)Wp)[j];
            ((ushort4*)WpB)[j] = make_ushort4(f2b(v.x), f2b(v.y), f2b(v.z), f2b(v.w));
        } else if (id < 1015808) {
            int j = id - 983040;
            W2aT[j] = f2b(W2[(size_t)(j & 511) * LL + (j >> 9)]);
        } else {
            int j = id - 1015808;
            W2bT[j] = f2b(W2[(size_t)((j & 511) + DD) * LL + (j >> 9)]);
        }
    } else {
        // zero ascore (4096) + pscore (512), contiguous: 4608 floats, 18 blocks
        int idx = (blk - 4096) * 256 + threadIdx.x;
        if (idx < 4608) scores[idx] = 0.f;
    }
}

extern "C" void kernel_launch(void* const* d_in, const int* in_sizes, int n_in,
                              void* d_out, int out_size, void* d_ws, size_t ws_size,
                              hipStream_t stream) {
    const float* span   = (const float*)d_in[0];
    const int*   preds  = (const int*)d_in[1];
    const int*   labels = (const int*)d_in[2];
    const float* Wp     = (const float*)d_in[4];
    const float* bp_    = (const float*)d_in[5];
    const float* Wa     = (const float*)d_in[6];
    const float* ba_    = (const float*)d_in[7];
    const float* wp     = (const float*)d_in[8];
    const float* wa     = (const float*)d_in[9];
    const float* W1     = (const float*)d_in[10];
    const float* W2     = (const float*)d_in[11];
    const float* bias   = (const float*)d_in[12];
    float* out = (float*)d_out;
    char* ws = (char*)d_ws;

    ushort_t* spanB  = (ushort_t*)(ws + 0);          //  4,194,304
    ushort_t* predB  = (ushort_t*)(ws + 4194304);    //    524,288
    ushort_t* WaB    = (ushort_t*)(ws + 4718592);    //    524,288
    ushort_t* WpB    = (ushort_t*)(ws + 5242880);    //    524,288
    ushort_t* W2aT   = (ushort_t*)(ws + 5767168);    //     65,536
    ushort_t* W2bT   = (ushort_t*)(ws + 5832704);    //     65,536
    ushort_t* UB     = (ushort_t*)(ws + 39452672);   // 33,554,432
    float*    ascore = (float*)(ws + 73007104);      //     16,384
    float*    pscore = (float*)(ws + 73023488);      //      2,048
    float*    spanW2 = (float*)(ws + 73025536);      //  1,048,576
    float*    predW2 = (float*)(ws + 74074112);      //    131,072

    hipFuncSetAttribute((const void*)k_U_small,
                        hipFuncAttributeMaxDynamicSharedMemorySize, 147456);
    hipFuncSetAttribute((const void*)k_out256,
                        hipFuncAttributeMaxDynamicSharedMemorySize, 98304);

    // scores zeroed by k_prep tail blocks (stream-ordered before k_U_small)
    k_prep<<<4114, 256, 0, stream>>>(span, preds, labels, Wa, Wp, W2,
                                     spanB, predB, WaB, WpB, W2aT, W2bT,
                                     out, ascore);

    k_U_small<<<436, 512, 147456, stream>>>(predB, W1, UB,
                                            spanB, WaB, WpB, W2bT, W2aT,
                                            ba_, bp_, wa, wp,
                                            ascore, pscore, spanW2, predW2);

    k_out256<<<256, 512, 98304, stream>>>(spanB, UB, spanW2, predW2,
                                          ascore, pscore, bias, out);
}

// Round 19
// 77.399 us; speedup vs baseline: 1.0749x; 1.0749x over previous
//
#include <hip/hip_runtime.h>
#include <hip/hip_bf16.h>

typedef __bf16 bf16x8 __attribute__((ext_vector_type(8)));
typedef float f32x4 __attribute__((ext_vector_type(4)));
typedef unsigned short ushort_t;

// B=8, P=64, S=512, D=512, L=64
#define SS 512
#define DD 512
#define LL 64

__device__ __forceinline__ ushort_t f2b(float f) {
    union { float f; unsigned u; } x; x.f = f;
    unsigned r = x.u + 0x7FFFu + ((x.u >> 16) & 1u);
    return (ushort_t)(r >> 16);
}

// async global->LDS, 16B per lane; LDS dest = wave-uniform base + lane*16
__device__ __forceinline__ void async16(const void* g, void* l) {
    __builtin_amdgcn_global_load_lds(
        (const __attribute__((address_space(1))) unsigned int*)g,
        (__attribute__((address_space(3))) unsigned int*)l, 16, 0, 0);
}

// =====================================================================
// 256x256 8-wave pipelined GEMM core (R4-proven) — k_out256 only.
// =====================================================================
__device__ __forceinline__ void stage_tile(const ushort_t* __restrict__ A, int lda,
                                           const ushort_t* __restrict__ Bt, int ldb,
                                           int k0, ushort_t* buf) {
    const int t = threadIdx.x;
    const int wbase = (t >> 6) << 10;              // wid*1024 bytes
#pragma unroll
    for (int p = 0; p < 2; p++) {
        int row = (p << 7) + (t >> 2);             // dest row = x>>6
        int kg = (t & 3) ^ ((t >> 3) & 3);         // slot ^ ((row>>1)&3)
        async16(A + (size_t)row * lda + k0 + kg * 8,
                (char*)buf + (p << 13) + wbase);
        async16(Bt + (size_t)row * ldb + k0 + kg * 8,
                (char*)(buf + 8192) + (p << 13) + wbase);
    }
}

__device__ __forceinline__ void gemm256(const ushort_t* __restrict__ A, int lda,
                                        const ushort_t* __restrict__ Bt, int ldb,
                                        ushort_t* lds, f32x4 (&acc)[8][4]) {
    const int t = threadIdx.x;
    const int lane = t & 63, wid = t >> 6;
    const int wm = wid >> 2, wn = wid & 3;
    const int r15 = lane & 15, kg = lane >> 4;
    const int sx = ((kg ^ ((r15 >> 1) & 3)) << 4);   // swizzled 16B slot byte
    const f32x4 z4 = {0.f, 0.f, 0.f, 0.f};
#pragma unroll
    for (int i = 0; i < 8; i++)
#pragma unroll
        for (int j = 0; j < 4; j++) acc[i][j] = z4;

    stage_tile(A, lda, Bt, ldb, 0, lds);            // tile 0 -> buf0
    stage_tile(A, lda, Bt, ldb, 32, lds + 16384);   // tile 1 -> buf1

    for (int T = 0; T < 16; ++T) {
        if (T < 15) asm volatile("s_waitcnt vmcnt(4)" ::: "memory");
        else        asm volatile("s_waitcnt vmcnt(0)" ::: "memory");
        __builtin_amdgcn_s_barrier();
        __builtin_amdgcn_sched_barrier(0);
        const ushort_t* bufA = lds + (T % 3) * 16384;
        const ushort_t* bufB = bufA + 8192;
        const char* pa = (const char*)bufA + (wm * 128 + r15) * 64 + sx;
        const char* pb = (const char*)bufB + (wn * 64 + r15) * 64 + sx;
        bf16x8 af[8], bf[4];
#pragma unroll
        for (int mf = 0; mf < 8; mf++) af[mf] = *(const bf16x8*)(pa + mf * 1024);
#pragma unroll
        for (int nf = 0; nf < 4; nf++) bf[nf] = *(const bf16x8*)(pb + nf * 1024);
        if (T + 2 < 16)
            stage_tile(A, lda, Bt, ldb, (T + 2) * 32, lds + ((T + 2) % 3) * 16384);
#pragma unroll
        for (int mf = 0; mf < 8; mf++)
#pragma unroll
            for (int nf = 0; nf < 4; nf++)
                acc[mf][nf] = __builtin_amdgcn_mfma_f32_16x16x32_bf16(
                    af[mf], bf[nf], acc[mf][nf], 0, 0, 0);
    }
    __syncthreads();    // all reads done; LDS free for epilogue reuse
}

// =====================================================================
// U-core R16 (best): BM=256, BN=128, 512 threads as 8 waves (2m x 4n;
// each wave 128x32 output, acc[8][2]). A via gload_lds 3x16KB (48KB);
// B = direct W1 f32 column gather, fb[2][8] = 16 loads/lane/step.
// vmcnt(2) counted schedule.
// =====================================================================
__device__ __forceinline__ void stageA2(const ushort_t* __restrict__ A,
                                        int k0, ushort_t* buf) {
    const int t = threadIdx.x;
    const int wbase = (t >> 6) << 10;
#pragma unroll
    for (int p = 0; p < 2; p++) {
        int row = (p << 7) + (t >> 2);
        int kg = (t & 3) ^ ((t >> 3) & 3);
        async16(A + (size_t)row * DD + k0 + kg * 8, (char*)buf + (p << 13) + wbase);
    }
}

__device__ __forceinline__ void gemm256x128_w1(const ushort_t* __restrict__ predB,
                                               const float* __restrict__ W1le,
                                               ushort_t* lds, f32x4 (&acc)[8][2]) {
    const int t = threadIdx.x;
    const int lane = t & 63, wid = t >> 6;
    const int wm = wid >> 2, wn = wid & 3;          // 2m x 4n
    const int r15 = lane & 15, kg = lane >> 4;
    const int sx = ((kg ^ ((r15 >> 1) & 3)) << 4);
    const f32x4 z4 = {0.f, 0.f, 0.f, 0.f};
#pragma unroll
    for (int i = 0; i < 8; i++) { acc[i][0] = z4; acc[i][1] = z4; }

    // per-lane B base: row (kg*8) of this k-tile, column wn*32 + r15
    const float* bbase = W1le + (size_t)(kg * 8) * DD + wn * 32 + r15;
    float fb[2][8];                                  // 16 VGPR B staging
    auto loadB = [&](int k0) {
#pragma unroll
        for (int nf = 0; nf < 2; nf++)
#pragma unroll
            for (int j = 0; j < 8; j++)
                fb[nf][j] = bbase[(size_t)(k0 + j) * DD + nf * 16];
    };

    loadB(0);                                        // B(0) [16 vm] — long pole first
    stageA2(predB, 0, lds);                          // A(0) [2 vm]
    stageA2(predB, 32, lds + 8192);                  // A(1) [2 vm]

    for (int T = 0; T < 16; ++T) {
        if (T < 15) asm volatile("s_waitcnt vmcnt(2)" ::: "memory");
        else        asm volatile("s_waitcnt vmcnt(0)" ::: "memory");
        __builtin_amdgcn_s_barrier();
        __builtin_amdgcn_sched_barrier(0);
        // cvt B(T) f32 -> bf16 frags (reads fb before next loadB overwrites)
        bf16x8 bf[2];
#pragma unroll
        for (int nf = 0; nf < 2; nf++)
#pragma unroll
            for (int j = 0; j < 8; j++) bf[nf][j] = (__bf16)fb[nf][j];
        if (T + 1 < 16) loadB((T + 1) * 32);         // B(T+1) [16 vm]
        if (T + 2 < 16) stageA2(predB, (T + 2) * 32, lds + ((T + 2) % 3) * 8192);
        const char* pa = (const char*)(lds + (T % 3) * 8192)
                         + (wm * 128 + r15) * 64 + sx;
        bf16x8 af[8];
#pragma unroll
        for (int mf = 0; mf < 8; mf++) af[mf] = *(const bf16x8*)(pa + mf * 1024);
#pragma unroll
        for (int mf = 0; mf < 8; mf++)
#pragma unroll
            for (int nf = 0; nf < 2; nf++)
                acc[mf][nf] = __builtin_amdgcn_mfma_f32_16x16x32_bf16(
                    af[mf], bf[nf], acc[mf][nf], 0, 0, 0);
    }
    __syncthreads();
}

// =====================================================================
// merged small + U kernel, 512 threads, 48KB dynamic LDS.
// blocks [0,180): small GEMMs (drain early; U backfills).
// blocks [180,692): U GEMM, BM=256 BN=128 — 512 blocks, ~2/CU resident.
// XCD swizzle (512 = 8x64, bijective): m-pairs of one W1 slab co-XCD.
// =====================================================================
__global__ void __launch_bounds__(512, 2) k_U_small(
    const ushort_t* __restrict__ predB, const float* __restrict__ W1,
    ushort_t* __restrict__ UB,
    const ushort_t* __restrict__ spanB, const ushort_t* __restrict__ WaB,
    const ushort_t* __restrict__ WpB, const ushort_t* __restrict__ W2bT,
    const ushort_t* __restrict__ W2aT,
    const float* __restrict__ ba_, const float* __restrict__ bp_,
    const float* __restrict__ wa, const float* __restrict__ wp,
    float* ascore, float* pscore, float* spanW2, float* predW2) {
    extern __shared__ ushort_t lds[];
    const f32x4 z4 = {0.f, 0.f, 0.f, 0.f};
    const int t = threadIdx.x, lane = t & 63;
    const int r15 = lane & 15, kg = lane >> 4;
    if (blockIdx.x >= 180) {
        // ---------------- U role ----------------
        f32x4 acc[8][2];
        int u = blockIdx.x - 180;                    // 0..511
        int swz = (u & 7) * 64 + (u >> 3);           // bijective 512->512
        int m0 = (swz & 1) * 256;
        int nidx = swz >> 1;                         // 0..255 (128-wide panels)
        int n0 = nidx * 128;
        int l = nidx >> 2, e0 = (nidx & 3) * 128;
        gemm256x128_w1(predB + (size_t)m0 * DD,
                       W1 + (size_t)l * DD * DD + e0, lds, acc);
        const int wid = t >> 6;
        const int wm = wid >> 2, wn = wid & 3;
        ushort_t* my = lds + wid * 2048;             // 4KB/wave -> 32KB (<=48KB)
        int gm = m0 + wm * 128, gn = n0 + wn * 32;
#pragma unroll
        for (int ch = 0; ch < 2; ch++) {
#pragma unroll
            for (int mf2 = 0; mf2 < 4; mf2++)
#pragma unroll
                for (int nf = 0; nf < 2; nf++)
#pragma unroll
                    for (int j = 0; j < 4; j++)
                        my[(mf2 * 16 + kg * 4 + j) * 32 + nf * 16 + r15] =
                            f2b(acc[ch * 4 + mf2][nf][j]);
            // same-wave LDS RAW ordered by compiler lgkmcnt
#pragma unroll
            for (int pass = 0; pass < 4; pass++) {
                int row = pass * 16 + (lane >> 2);
                bf16x8 v = *(const bf16x8*)(my + row * 32 + (lane & 3) * 8);
                *(bf16x8*)(UB + (size_t)(gm + ch * 64 + row) * 32768 + gn
                           + (lane & 3) * 8) = v;
            }
        }
        return;
    }
    // ---------------- small role (512 threads; lower 256 active) ----------
    const bool act = t < 256;
    ushort_t* As = lds;              // 8KB
    ushort_t* Bs = lds + 4096;       // 8KB
    const int wid4 = (t >> 6) & 3;
    const int o0 = wid4 * 1024 + lane * 16;
    int blk = blockIdx.x;
    if (blk < 144) {
        const ushort_t *A, *Bt; const float *bias, *w; float* sc; int m0, n0;
        if (blk < 128) { A = spanB; Bt = WaB; bias = ba_; w = wa; sc = ascore;
                         m0 = (blk >> 2) * 128; n0 = (blk & 3) * 128; }
        else { int q = blk - 128; A = predB; Bt = WpB; bias = bp_; w = wp; sc = pscore;
               m0 = (q >> 2) * 128; n0 = (q & 3) * 128; }
        const ushort_t* Ab = A + (size_t)m0 * DD;
        const ushort_t* Bb = Bt + (size_t)n0 * DD;
        f32x4 acc[4][4];
#pragma unroll
        for (int i = 0; i < 4; i++)
#pragma unroll
            for (int j = 0; j < 4; j++) acc[i][j] = z4;
        int wr = (wid4 >> 1) * 64, wc = (wid4 & 1) * 64;
        for (int k0 = 0; k0 < DD; k0 += 32) {
            if (act) {
#pragma unroll
                for (int p = 0; p < 2; p++) {
                    int o = o0 + p * 4096;
                    async16(Ab + (size_t)(o >> 6) * DD + k0 + ((o & 63) >> 1), (char*)As + o);
                    async16(Bb + (size_t)(o >> 6) * DD + k0 + ((o & 63) >> 1), (char*)Bs + o);
                }
            }
            __syncthreads();
            if (act) {
                bf16x8 af[4], bf[4];
#pragma unroll
                for (int mf = 0; mf < 4; mf++)
                    af[mf] = *(const bf16x8*)(As + (wr + mf * 16 + r15) * 32 + kg * 8);
#pragma unroll
                for (int nf = 0; nf < 4; nf++)
                    bf[nf] = *(const bf16x8*)(Bs + (wc + nf * 16 + r15) * 32 + kg * 8);
#pragma unroll
                for (int mf = 0; mf < 4; mf++)
#pragma unroll
                    for (int nf = 0; nf < 4; nf++)
                        acc[mf][nf] = __builtin_amdgcn_mfma_f32_16x16x32_bf16(
                            af[mf], bf[nf], acc[mf][nf], 0, 0, 0);
            }
            __syncthreads();
        }
        if (act) {
#pragma unroll
            for (int mf = 0; mf < 4; mf++)
#pragma unroll
                for (int j = 0; j < 4; j++) {
                    float v = 0.f;
#pragma unroll
                    for (int nf = 0; nf < 4; nf++) {
                        int col = n0 + wc + nf * 16 + r15;
                        float c = acc[mf][nf][j] + bias[col];
                        if (c > 0.f) v += c * w[col];
                    }
                    v += __shfl_xor(v, 1); v += __shfl_xor(v, 2);
                    v += __shfl_xor(v, 4); v += __shfl_xor(v, 8);
                    if (r15 == 0) atomicAdd(&sc[m0 + wr + mf * 16 + kg * 4 + j], v);
                }
        }
    } else {
        int q = blk - 144;
        const ushort_t *A, *Bt; float* C; int m0;
        if (q < 32) { A = spanB; Bt = W2bT; C = spanW2; m0 = q * 128; }
        else { A = predB; Bt = W2aT; C = predW2; m0 = (q - 32) * 128; }
        const ushort_t* Ab = A + (size_t)m0 * DD;
        f32x4 acc[4][2];
#pragma unroll
        for (int i = 0; i < 4; i++) { acc[i][0] = z4; acc[i][1] = z4; }
        int wr = (wid4 >> 1) * 64, wc = (wid4 & 1) * 32;
        for (int k0 = 0; k0 < DD; k0 += 32) {
            if (act) {
#pragma unroll
                for (int p = 0; p < 2; p++) {
                    int o = o0 + p * 4096;
                    async16(Ab + (size_t)(o >> 6) * DD + k0 + ((o & 63) >> 1), (char*)As + o);
                }
                int o = o0;
                async16(Bt + (size_t)(o >> 6) * DD + k0 + ((o & 63) >> 1), (char*)Bs + o);
            }
            __syncthreads();
            if (act) {
                bf16x8 af[4], bf[2];
#pragma unroll
                for (int mf = 0; mf < 4; mf++)
                    af[mf] = *(const bf16x8*)(As + (wr + mf * 16 + r15) * 32 + kg * 8);
#pragma unroll
                for (int nf = 0; nf < 2; nf++)
                    bf[nf] = *(const bf16x8*)(Bs + (wc + nf * 16 + r15) * 32 + kg * 8);
#pragma unroll
                for (int mf = 0; mf < 4; mf++)
#pragma unroll
                    for (int nf = 0; nf < 2; nf++)
                        acc[mf][nf] = __builtin_amdgcn_mfma_f32_16x16x32_bf16(
                            af[mf], bf[nf], acc[mf][nf], 0, 0, 0);
            }
            __syncthreads();
        }
        if (act) {
#pragma unroll
            for (int mf = 0; mf < 4; mf++)
#pragma unroll
                for (int nf = 0; nf < 2; nf++)
#pragma unroll
                    for (int j = 0; j < 4; j++) {
                        int m = m0 + wr + mf * 16 + kg * 4 + j;
                        int n = wc + nf * 16 + r15;
                        C[(size_t)m * LL + n] = acc[mf][nf][j];
                    }
        }
    }
}

// ---- out GEMM 256 + fused epilogue: per b, C[s, p*64+l] ----
__global__ void __launch_bounds__(512, 2) k_out256(const ushort_t* __restrict__ spanB,
    const ushort_t* __restrict__ UB, const float* __restrict__ spanW2,
    const float* __restrict__ predW2, const float* __restrict__ ascore,
    const float* __restrict__ pscore, const float* __restrict__ bias,
    float* __restrict__ out) {
    extern __shared__ ushort_t lds[];
    f32x4 acc[8][4];
    int swz = (blockIdx.x & 7) * 32 + (blockIdx.x >> 3);   // 256 -> 256 bijective
    int b = swz >> 5, r = swz & 31;
    int m0 = (r & 1) * 256, n0 = (r >> 1) * 256;
    gemm256(spanB + ((size_t)b * SS + m0) * DD, DD,
            UB + ((size_t)b * 4096 + n0) * DD, DD, lds, acc);
    const int t = threadIdx.x, lane = t & 63, wid = t >> 6;
    const int wm = wid >> 2, wn = wid & 3, r15 = lane & 15, kg = lane >> 4;
    float cn[4]; int nn[4];
#pragma unroll
    for (int nf = 0; nf < 4; nf++) {
        int n = n0 + wn * 64 + nf * 16 + r15;
        nn[nf] = n;
        cn[nf] = bias[n & 63] + predW2[b * 4096 + n] + pscore[b * 64 + (n >> 6)];
    }
#pragma unroll
    for (int mf = 0; mf < 8; mf++)
#pragma unroll
        for (int j = 0; j < 4; j++) {
            int s = m0 + wm * 128 + mf * 16 + kg * 4 + j;
            float as_ = ascore[b * SS + s];
            const float* sw = spanW2 + ((size_t)b * SS + s) * LL;
#pragma unroll
            for (int nf = 0; nf < 4; nf++) {
                int n = nn[nf], l = n & 63, p = n >> 6;
                float v = acc[mf][nf][j] + cn[nf] + as_ + sw[l];
                if (l == LL - 1) v = 0.f;
                out[(((size_t)b * 64 + p) * SS + s) * LL + l] = v;
            }
        }
}

// ---- fast prep: bf16 conversions, gather, W2^T, labels, score zero-init ----
__global__ __launch_bounds__(256) void k_prep(
    const float* __restrict__ span, const int* __restrict__ preds,
    const int* __restrict__ labels, const float* __restrict__ Wa,
    const float* __restrict__ Wp, const float* __restrict__ W2,
    ushort_t* spanB, ushort_t* predB, ushort_t* WaB, ushort_t* WpB,
    ushort_t* W2aT, ushort_t* W2bT, float* out, float* scores) {
    int blk = blockIdx.x;
    if (blk < 4096) {
        int id = blk * 256 + threadIdx.x;
        if (id < 524288) {
            float4 v = ((const float4*)span)[id];
            ((ushort4*)spanB)[id] = make_ushort4(f2b(v.x), f2b(v.y), f2b(v.z), f2b(v.w));
        } else if (id < 589824) {
            int j = id - 524288;
            int row = j >> 7, c4 = j & 127;
            int b = row >> 6;
            int idx = preds[row];
            float4 v = ((const float4*)(span + ((size_t)(b * SS + idx)) * DD))[c4];
            ((ushort4*)(predB + (size_t)row * DD))[c4] =
                make_ushort4(f2b(v.x), f2b(v.y), f2b(v.z), f2b(v.w));
        } else if (id < 851968) {
            int k = id - 589824;
            out[16777216 + k] = (float)labels[k];
        } else if (id < 917504) {
            int j = id - 851968;
            float4 v = ((const float4*)Wa)[j];
            ((ushort4*)WaB)[j] = make_ushort4(f2b(v.x), f2b(v.y), f2b(v.z), f2b(v.w));
        } else if (id < 983040) {
            int j = id - 917504;
            float4 v = ((const float4*)Wp)[j];
            ((ushort4*)WpB)[j] = make_ushort4(f2b(v.x), f2b(v.y), f2b(v.z), f2b(v.w));
        } else if (id < 1015808) {
            int j = id - 983040;
            W2aT[j] = f2b(W2[(size_t)(j & 511) * LL + (j >> 9)]);
        } else {
            int j = id - 1015808;
            W2bT[j] = f2b(W2[(size_t)((j & 511) + DD) * LL + (j >> 9)]);
        }
    } else {
        // zero ascore (4096) + pscore (512), contiguous: 4608 floats, 18 blocks
        int idx = (blk - 4096) * 256 + threadIdx.x;
        if (idx < 4608) scores[idx] = 0.f;
    }
}

extern "C" void kernel_launch(void* const* d_in, const int* in_sizes, int n_in,
                              void* d_out, int out_size, void* d_ws, size_t ws_size,
                              hipStream_t stream) {
    const float* span   = (const float*)d_in[0];
    const int*   preds  = (const int*)d_in[1];
    const int*   labels = (const int*)d_in[2];
    const float* Wp     = (const float*)d_in[4];
    const float* bp_    = (const float*)d_in[5];
    const float* Wa     = (const float*)d_in[6];
    const float* ba_    = (const float*)d_in[7];
    const float* wp     = (const float*)d_in[8];
    const float* wa     = (const float*)d_in[9];
    const float* W1     = (const float*)d_in[10];
    const float* W2     = (const float*)d_in[11];
    const float* bias   = (const float*)d_in[12];
    float* out = (float*)d_out;
    char* ws = (char*)d_ws;

    ushort_t* spanB  = (ushort_t*)(ws + 0);          //  4,194,304
    ushort_t* predB  = (ushort_t*)(ws + 4194304);    //    524,288
    ushort_t* WaB    = (ushort_t*)(ws + 4718592);    //    524,288
    ushort_t* WpB    = (ushort_t*)(ws + 5242880);    //    524,288
    ushort_t* W2aT   = (ushort_t*)(ws + 5767168);    //     65,536
    ushort_t* W2bT   = (ushort_t*)(ws + 5832704);    //     65,536
    ushort_t* UB     = (ushort_t*)(ws + 39452672);   // 33,554,432
    float*    ascore = (float*)(ws + 73007104);      //     16,384
    float*    pscore = (float*)(ws + 73023488);      //      2,048
    float*    spanW2 = (float*)(ws + 73025536);      //  1,048,576
    float*    predW2 = (float*)(ws + 74074112);      //    131,072

    hipFuncSetAttribute((const void*)k_U_small,
                        hipFuncAttributeMaxDynamicSharedMemorySize, 49152);
    hipFuncSetAttribute((const void*)k_out256,
                        hipFuncAttributeMaxDynamicSharedMemorySize, 98304);

    // scores zeroed by k_prep tail blocks (stream-ordered before k_U_small)
    k_prep<<<4114, 256, 0, stream>>>(span, preds, labels, Wa, Wp, W2,
                                     spanB, predB, WaB, WpB, W2aT, W2bT,
                                     out, ascore);

    k_U_small<<<692, 512, 49152, stream>>>(predB, W1, UB,
                                           spanB, WaB, WpB, W2bT, W2aT,
                                           ba_, bp_, wa, wp,
                                           ascore, pscore, spanW2, predW2);

    k_out256<<<256, 512, 98304, stream>>>(spanB, UB, spanW2, predW2,
                                          ascore, pscore, bias, out);
}